// Round 3
// baseline (730.030 us; speedup 1.0000x reference)
//
#include <hip/hip_runtime.h>

typedef unsigned short ushort_t;
typedef unsigned int uint_t;
typedef __attribute__((ext_vector_type(8))) short bf16x8;
typedef __attribute__((ext_vector_type(4))) float f32x4;

#define B_ROWS 32768
#define H_DIM 512
#define M_CHUNK 16384   // process B in 2 chunks -> h buffer is 16.8 MB, ws total ~26 MB

// LDS row strides (elements). 40 elems = 80 B = 20 dwords -> staggered banks.
#define AS_STRIDE 40
#define BS_STRIDE 40

__device__ inline ushort_t f2bf(float f) {
  union { float f; uint_t u; } v; v.f = f;
  uint_t r = (v.u + 0x7FFFu + ((v.u >> 16) & 1u)) >> 16;  // RNE
  return (ushort_t)r;
}
__device__ inline float fast_sigmoid(float x) { return 1.0f / (1.0f + __expf(-x)); }
__device__ inline float fast_tanh(float x) { return 1.0f - 2.0f / (__expf(2.0f * x) + 1.0f); }

__device__ inline bf16x8 cvt8(const float* p) {
  f32x4 u0 = *(const f32x4*)p;
  f32x4 u1 = *(const f32x4*)(p + 4);
  bf16x8 r;
  #pragma unroll
  for (int i = 0; i < 4; ++i) { r[i] = (short)f2bf(u0[i]); r[i + 4] = (short)f2bf(u1[i]); }
  return r;
}

// ---------------------------------------------------------------------------
// Weight transpose + fp32->bf16: src (K x 512) fp32 row-major -> dst (512 x K) bf16.
// ---------------------------------------------------------------------------
__global__ __launch_bounds__(256)
void transpose_k(const float* __restrict__ src, ushort_t* __restrict__ dst, int K) {
  __shared__ ushort_t tile[32][33];
  const int n0 = blockIdx.x * 32;
  const int k0 = blockIdx.y * 32;
  const int tx = threadIdx.x;   // 0..31
  const int ty = threadIdx.y;   // 0..7
  #pragma unroll
  for (int j = 0; j < 32; j += 8)
    tile[ty + j][tx] = f2bf(src[(size_t)(k0 + ty + j) * H_DIM + n0 + tx]);
  __syncthreads();
  #pragma unroll
  for (int j = 0; j < 32; j += 8)
    dst[(size_t)(n0 + ty + j) * K + k0 + tx] = tile[tx][ty + j];
}

// ---------------------------------------------------------------------------
// Fused gated GEMM:  val = tanh(X@Wh + bh) * sigmoid(X@Wg + bg)
// X = row-wise concat of NSEG (rows x 512) matrices. Segment 0 may be bf16
// (b0 != null, from ws); other segments fp32 (converted to bf16 on stage).
// WTh/WTg: bf16 transposed weights (512 x K), K = NSEG*512.
// OUT_BF16: write ushort (layer-1 h). Else fp32.
// SELECT: out[m][n] = g==0 ? val : (g==1 ? existing out[m][n] : 0)
// Tile: BM=128, BN=64 (x2 gates), BK=32. 256 threads = 4 waves.
// ---------------------------------------------------------------------------
template<int NSEG, bool OUT_BF16, bool SELECT>
__global__ __launch_bounds__(256, 2)
void gate_gemm(const float* __restrict__ f0, const float* __restrict__ f1,
               const float* __restrict__ f2, const ushort_t* __restrict__ b0,
               const ushort_t* __restrict__ WTh, const ushort_t* __restrict__ WTg,
               const float* __restrict__ bh, const float* __restrict__ bg,
               void* __restrict__ out_v, const int* __restrict__ group)
{
  constexpr int K = NSEG * 512;
  __shared__ ushort_t As[128 * AS_STRIDE];   // [m][k]
  __shared__ ushort_t Bhs[64 * BS_STRIDE];   // [n][k]
  __shared__ ushort_t Bgs[64 * BS_STRIDE];

  const int t = threadIdx.x;
  const int lane = t & 63;
  const int wave = t >> 6;
  const int m_blk = blockIdx.x * 128;
  const int n_blk = blockIdx.y * 64;

  const f32x4 zero4 = {0.f, 0.f, 0.f, 0.f};
  f32x4 acch[2][4], accg[2][4];
  #pragma unroll
  for (int i = 0; i < 2; ++i)
    #pragma unroll
    for (int j = 0; j < 4; ++j) { acch[i][j] = zero4; accg[i][j] = zero4; }

  const int srow = t >> 2;   // staging row (0..63)
  const int schk = t & 3;    // 8-elem (16B bf16 / 32B fp32) chunk in 32-elem row
  const int q = lane >> 4;   // quad
  const int col = lane & 15;

  #pragma unroll
  for (int s = 0; s < NSEG; ++s) {
    const bool seg_bf16 = (s == 0) && (b0 != nullptr);
    const float* fp = (s == 0) ? f0 : ((s == 1) ? f1 : f2);
    for (int kk = 0; kk < 512; kk += 32) {
      const int k0 = s * 512 + kk;
      bf16x8 va0, va1;
      if (seg_bf16) {
        va0 = *(const bf16x8*)(b0 + (size_t)(m_blk + srow) * H_DIM + kk + schk * 8);
        va1 = *(const bf16x8*)(b0 + (size_t)(m_blk + 64 + srow) * H_DIM + kk + schk * 8);
      } else {
        va0 = cvt8(fp + (size_t)(m_blk + srow) * H_DIM + kk + schk * 8);
        va1 = cvt8(fp + (size_t)(m_blk + 64 + srow) * H_DIM + kk + schk * 8);
      }
      bf16x8 vbh = *(const bf16x8*)(WTh + (size_t)(n_blk + srow) * K + k0 + schk * 8);
      bf16x8 vbg = *(const bf16x8*)(WTg + (size_t)(n_blk + srow) * K + k0 + schk * 8);
      __syncthreads();   // previous compute done before overwriting LDS
      *(bf16x8*)&As[srow * AS_STRIDE + schk * 8] = va0;
      *(bf16x8*)&As[(64 + srow) * AS_STRIDE + schk * 8] = va1;
      *(bf16x8*)&Bhs[srow * BS_STRIDE + schk * 8] = vbh;
      *(bf16x8*)&Bgs[srow * BS_STRIDE + schk * 8] = vbg;
      __syncthreads();

      // A frag: A[m=lane&15][k=quad*8+j]; B frag: B[n=lane&15][k=quad*8+j]
      bf16x8 af0 = *(const bf16x8*)&As[(wave * 32 + col) * AS_STRIDE + q * 8];
      bf16x8 af1 = *(const bf16x8*)&As[(wave * 32 + 16 + col) * AS_STRIDE + q * 8];
      #pragma unroll
      for (int ns = 0; ns < 4; ++ns) {
        bf16x8 bfh = *(const bf16x8*)&Bhs[(ns * 16 + col) * BS_STRIDE + q * 8];
        bf16x8 bfg = *(const bf16x8*)&Bgs[(ns * 16 + col) * BS_STRIDE + q * 8];
        acch[0][ns] = __builtin_amdgcn_mfma_f32_16x16x32_bf16(af0, bfh, acch[0][ns], 0, 0, 0);
        acch[1][ns] = __builtin_amdgcn_mfma_f32_16x16x32_bf16(af1, bfh, acch[1][ns], 0, 0, 0);
        accg[0][ns] = __builtin_amdgcn_mfma_f32_16x16x32_bf16(af0, bfg, accg[0][ns], 0, 0, 0);
        accg[1][ns] = __builtin_amdgcn_mfma_f32_16x16x32_bf16(af1, bfg, accg[1][ns], 0, 0, 0);
      }
    }
  }

  // Epilogue. C/D layout: col = lane&15, row = quad*4 + reg  (m89/m91).
  #pragma unroll
  for (int ms = 0; ms < 2; ++ms) {
    const int m_base = m_blk + wave * 32 + ms * 16 + q * 4;
    #pragma unroll
    for (int ns = 0; ns < 4; ++ns) {
      const int n = n_blk + ns * 16 + col;
      const float bhv = bh[n];
      const float bgv = bg[n];
      #pragma unroll
      for (int r = 0; r < 4; ++r) {
        const int m = m_base + r;
        float hv = fast_tanh(acch[ms][ns][r] + bhv) * fast_sigmoid(accg[ms][ns][r] + bgv);
        if (OUT_BF16) {
          ((ushort_t*)out_v)[(size_t)m * H_DIM + n] = f2bf(hv);
        } else {
          float* po = (float*)out_v + (size_t)m * H_DIM + n;
          if (SELECT) {
            const int g = group[m];
            const float rv = *po;   // right_out written by previous launch
            hv = (g == 0) ? hv : ((g == 1) ? rv : 0.0f);
          }
          *po = hv;
        }
      }
    }
  }
}

__global__ __launch_bounds__(256)
void mask_k(const int* __restrict__ group, float* __restrict__ out_mask) {
  const int i = blockIdx.x * 256 + threadIdx.x;
  out_mask[i] = (group[i] == 2) ? 1.0f : 0.0f;
}

extern "C" void kernel_launch(void* const* d_in, const int* in_sizes, int n_in,
                              void* d_out, int out_size, void* d_ws, size_t ws_size,
                              hipStream_t stream) {
  const float* node_hidden     = (const float*)d_in[0];
  const float* node_context    = (const float*)d_in[1];
  const float* label_embedding = (const float*)d_in[2];
  const float* left_embedding  = (const float*)d_in[3];
  const int*   group           = (const int*)d_in[4];
  const float* Wl1h = (const float*)d_in[5];
  const float* bl1h = (const float*)d_in[6];
  const float* Wl1g = (const float*)d_in[7];
  const float* bl1g = (const float*)d_in[8];
  const float* Wl2h = (const float*)d_in[9];
  const float* bl2h = (const float*)d_in[10];
  const float* Wl2g = (const float*)d_in[11];
  const float* bl2g = (const float*)d_in[12];
  const float* Wr1h = (const float*)d_in[13];
  const float* br1h = (const float*)d_in[14];
  const float* Wr1g = (const float*)d_in[15];
  const float* br1g = (const float*)d_in[16];
  const float* Wr2h = (const float*)d_in[17];
  const float* br2h = (const float*)d_in[18];
  const float* Wr2g = (const float*)d_in[19];
  const float* br2g = (const float*)d_in[20];

  // Workspace (~26.2 MB): 8 bf16 WT buffers (9.4 MB) + one bf16 h chunk (16.8 MB).
  char* ws = (char*)d_ws;
  const size_t w3 = (size_t)512 * 1536;
  const size_t w1 = (size_t)512 * 512;
  const size_t w2 = (size_t)512 * 1024;
  ushort_t* WT_l1h = (ushort_t*)ws;   ws += w3 * 2;
  ushort_t* WT_l1g = (ushort_t*)ws;   ws += w3 * 2;
  ushort_t* WT_r1h = (ushort_t*)ws;   ws += w3 * 2;
  ushort_t* WT_r1g = (ushort_t*)ws;   ws += w3 * 2;
  ushort_t* WT_l2h = (ushort_t*)ws;   ws += w1 * 2;
  ushort_t* WT_l2g = (ushort_t*)ws;   ws += w1 * 2;
  ushort_t* WT_r2h = (ushort_t*)ws;   ws += w2 * 2;
  ushort_t* WT_r2g = (ushort_t*)ws;   ws += w2 * 2;
  ushort_t* h_buf  = (ushort_t*)ws;   ws += (size_t)M_CHUNK * H_DIM * 2;

  float* out_children = (float*)d_out;
  float* out_mask     = out_children + (size_t)B_ROWS * H_DIM;

  dim3 tb(32, 8);
  transpose_k<<<dim3(16, 48), tb, 0, stream>>>(Wl1h, WT_l1h, 1536);
  transpose_k<<<dim3(16, 48), tb, 0, stream>>>(Wl1g, WT_l1g, 1536);
  transpose_k<<<dim3(16, 48), tb, 0, stream>>>(Wr1h, WT_r1h, 1536);
  transpose_k<<<dim3(16, 48), tb, 0, stream>>>(Wr1g, WT_r1g, 1536);
  transpose_k<<<dim3(16, 16), tb, 0, stream>>>(Wl2h, WT_l2h, 512);
  transpose_k<<<dim3(16, 16), tb, 0, stream>>>(Wl2g, WT_l2g, 512);
  transpose_k<<<dim3(16, 32), tb, 0, stream>>>(Wr2h, WT_r2h, 1024);
  transpose_k<<<dim3(16, 32), tb, 0, stream>>>(Wr2g, WT_r2g, 1024);

  dim3 gg(M_CHUNK / 128, H_DIM / 64);   // (128, 8)
  dim3 gb(256);
  for (int c = 0; c < B_ROWS / M_CHUNK; ++c) {
    const size_t ro = (size_t)c * M_CHUNK;          // row offset
    const float* nh = node_hidden     + ro * H_DIM;
    const float* nc = node_context    + ro * H_DIM;
    const float* le = label_embedding + ro * H_DIM;
    const float* lf = left_embedding  + ro * H_DIM;
    float* oc = out_children + ro * H_DIM;
    const int* gp = group + ro;
    // 1) h_r = gate1_r([nh|nc|le])          (bf16 -> ws)
    gate_gemm<3, true, false><<<gg, gb, 0, stream>>>(nh, nc, le, nullptr,
        WT_r1h, WT_r1g, br1h, br1g, h_buf, nullptr);
    // 2) right_out = gate2_r([h_r|lf])      (fp32 -> d_out)
    gate_gemm<2, false, false><<<gg, gb, 0, stream>>>(nullptr, lf, nullptr, h_buf,
        WT_r2h, WT_r2g, br2h, br2g, oc, nullptr);
    // 3) h_l = gate1_l([nh|nc|le])          (bf16 -> ws, reuse)
    gate_gemm<3, true, false><<<gg, gb, 0, stream>>>(nh, nc, le, nullptr,
        WT_l1h, WT_l1g, bl1h, bl1g, h_buf, nullptr);
    // 4) out = g==0 ? gate2_l(h_l) : (g==1 ? right_out : 0)
    gate_gemm<1, false, true><<<gg, gb, 0, stream>>>(nullptr, nullptr, nullptr, h_buf,
        WT_l2h, WT_l2g, bl2h, bl2g, oc, gp);
  }
  mask_k<<<B_ROWS / 256, 256, 0, stream>>>(group, out_mask);
}

// Round 4
// 531.122 us; speedup vs baseline: 1.3745x; 1.3745x over previous
//
#include <hip/hip_runtime.h>

typedef unsigned short ushort_t;
typedef unsigned int uint_t;
typedef __attribute__((ext_vector_type(8))) short bf16x8;
typedef __attribute__((ext_vector_type(4))) float f32x4;

#define B_ROWS 32768
#define H_DIM 512
#define M_CHUNK 16384   // fallback path chunking (R3-proven)

// LDS row strides (elements). 40 elems = 80 B = 20 dwords -> staggered banks.
#define AS_STRIDE 40
#define BS_STRIDE 40

__device__ inline ushort_t f2bf(float f) {
  union { float f; uint_t u; } v; v.f = f;
  uint_t r = (v.u + 0x7FFFu + ((v.u >> 16) & 1u)) >> 16;  // RNE
  return (ushort_t)r;
}
__device__ inline float fast_sigmoid(float x) { return 1.0f / (1.0f + __expf(-x)); }
__device__ inline float fast_tanh(float x) { return 1.0f - 2.0f / (__expf(2.0f * x) + 1.0f); }

__device__ inline bf16x8 cvt8(const float* p) {
  f32x4 u0 = *(const f32x4*)p;
  f32x4 u1 = *(const f32x4*)(p + 4);
  bf16x8 r;
  #pragma unroll
  for (int i = 0; i < 4; ++i) { r[i] = (short)f2bf(u0[i]); r[i + 4] = (short)f2bf(u1[i]); }
  return r;
}

// ---------------------------------------------------------------------------
// Fused weight transposes: 8 matrices in one launch (blockIdx.z selects).
// src (K x 512) fp32 row-major -> dst (512 x K) bf16 row-major.
// ---------------------------------------------------------------------------
struct TransposeParams {
  const float* src[8];
  ushort_t* dst[8];
  int K[8];
};

__global__ __launch_bounds__(256)
void transpose_all(TransposeParams tp) {
  const int z = blockIdx.z;
  const int K = tp.K[z];
  const int k0 = blockIdx.y * 32;
  if (k0 >= K) return;
  const float* src = tp.src[z];
  ushort_t* dst = tp.dst[z];
  __shared__ ushort_t tile[32][33];
  const int n0 = blockIdx.x * 32;
  const int tx = threadIdx.x;   // 0..31
  const int ty = threadIdx.y;   // 0..7
  #pragma unroll
  for (int j = 0; j < 32; j += 8)
    tile[ty + j][tx] = f2bf(src[(size_t)(k0 + ty + j) * H_DIM + n0 + tx]);
  __syncthreads();
  #pragma unroll
  for (int j = 0; j < 32; j += 8)
    dst[(size_t)(n0 + ty + j) * K + k0 + tx] = tile[tx][ty + j];
}

// ---------------------------------------------------------------------------
// Compaction: stable partition of rows by group. Single block, 1024 threads,
// 32 rows/thread, Hillis-Steele scan in LDS. Writes idx0 (g==0), idx1 (g==1),
// cnt[0]=count0, cnt[1]=count1; pads idx tails (to 128-multiple) with 0.
// ---------------------------------------------------------------------------
__global__ __launch_bounds__(1024)
void compact_k(const int* __restrict__ group, int* __restrict__ idx0,
               int* __restrict__ idx1, int* __restrict__ cnt) {
  __shared__ int s0[1024], s1[1024];
  const int t = threadIdx.x;
  const int base = t * 32;
  int g[32];
  int c0 = 0, c1 = 0;
  #pragma unroll
  for (int i = 0; i < 32; ++i) {
    g[i] = group[base + i];
    c0 += (g[i] == 0);
    c1 += (g[i] == 1);
  }
  s0[t] = c0; s1[t] = c1;
  __syncthreads();
  for (int off = 1; off < 1024; off <<= 1) {
    int a0 = (t >= off) ? s0[t - off] : 0;
    int a1 = (t >= off) ? s1[t - off] : 0;
    __syncthreads();
    s0[t] += a0; s1[t] += a1;
    __syncthreads();
  }
  const int total0 = s0[1023], total1 = s1[1023];
  int off0 = s0[t] - c0;   // exclusive prefix
  int off1 = s1[t] - c1;
  #pragma unroll
  for (int i = 0; i < 32; ++i) {
    if (g[i] == 0) idx0[off0++] = base + i;
    if (g[i] == 1) idx1[off1++] = base + i;
  }
  if (t == 0) { cnt[0] = total0; cnt[1] = total1; }
  const int p0 = (total0 + 127) & ~127;
  const int p1 = (total1 + 127) & ~127;
  for (int j = total0 + t; j < p0; j += 1024) idx0[j] = 0;
  for (int j = total1 + t; j < p1; j += 1024) idx1[j] = 0;
}

// ---------------------------------------------------------------------------
// Compacted fused gated GEMM. gridDim.z = 2 (z picks cfg: left / right path).
//   val = tanh(X@Wh + bh) * sigmoid(X@Wg + bg)
// X rows are compacted: fp32 segments gathered via idx; optional bf16 seg0
// (hidden h) is compact-contiguous in h_buf (z=1 offset by pad(cnt[0]) rows).
// out_mode 0: write bf16 h rows (compact). out_mode 1: fp32 scatter via idx.
// Tile BM=128, BN=64 (x2 gates), BK=32, 256 threads = 4 waves.
// ---------------------------------------------------------------------------
struct GemmCfg {
  const float* f0; const float* f1; const float* f2;  // fp32 segments
  const ushort_t* WTh; const ushort_t* WTg;           // (512 x K) bf16
  const float* bh; const float* bg;
  const int* idx;
  int nseg;          // K = nseg*512
  int b0_is_h;       // seg0 comes from h_buf (bf16, compact, no idx)
  int out_mode;      // 0 = bf16 h compact, 1 = fp32 scatter via idx
  int cnt_slot;      // which count bounds M
  int h_off_cnt0;    // h base offset = pad(cnt[0]) rows
};
struct GemmParams {
  GemmCfg c[2];
  ushort_t* h_buf;
  float* out;
  const int* cnt;
};

__global__ __launch_bounds__(256, 2)
void gate_gemm_c(GemmParams p) {
  const GemmCfg cfg = p.c[blockIdx.z];
  const int count = p.cnt[cfg.cnt_slot];
  const int count_pad = (count + 127) & ~127;
  const int m_blk = blockIdx.x * 128;
  if (m_blk >= count_pad) return;
  const int c0p = (p.cnt[0] + 127) & ~127;
  ushort_t* hbase = p.h_buf + (size_t)(cfg.h_off_cnt0 ? c0p : 0) * H_DIM;
  const int K = cfg.nseg * 512;

  __shared__ ushort_t As[128 * AS_STRIDE];   // [m][k]
  __shared__ ushort_t Bhs[64 * BS_STRIDE];   // [n][k]
  __shared__ ushort_t Bgs[64 * BS_STRIDE];

  const int t = threadIdx.x;
  const int lane = t & 63;
  const int wave = t >> 6;
  const int n_blk = blockIdx.y * 64;

  const f32x4 zero4 = {0.f, 0.f, 0.f, 0.f};
  f32x4 acch[2][4], accg[2][4];
  #pragma unroll
  for (int i = 0; i < 2; ++i)
    #pragma unroll
    for (int j = 0; j < 4; ++j) { acch[i][j] = zero4; accg[i][j] = zero4; }

  const int srow = t >> 2;   // staging row (0..63)
  const int schk = t & 3;    // 8-elem chunk in 32-elem k-slice
  const int q = lane >> 4;   // quad
  const int col = lane & 15;

  for (int s = 0; s < cfg.nseg; ++s) {
    const bool segbf = (s == 0) && cfg.b0_is_h;
    const float* fp = (s == 0) ? cfg.f0 : ((s == 1) ? cfg.f1 : cfg.f2);
    int pr0 = m_blk + srow, pr1 = m_blk + 64 + srow;
    if (!segbf && cfg.idx) { pr0 = cfg.idx[pr0]; pr1 = cfg.idx[pr1]; }
    const ushort_t* hb0 = hbase + (size_t)(m_blk + srow) * H_DIM;
    const ushort_t* hb1 = hbase + (size_t)(m_blk + 64 + srow) * H_DIM;
    for (int kk = 0; kk < 512; kk += 32) {
      const int k0 = s * 512 + kk;
      bf16x8 va0, va1;
      if (segbf) {
        va0 = *(const bf16x8*)(hb0 + kk + schk * 8);
        va1 = *(const bf16x8*)(hb1 + kk + schk * 8);
      } else {
        va0 = cvt8(fp + (size_t)pr0 * H_DIM + kk + schk * 8);
        va1 = cvt8(fp + (size_t)pr1 * H_DIM + kk + schk * 8);
      }
      bf16x8 vbh = *(const bf16x8*)(cfg.WTh + (size_t)(n_blk + srow) * K + k0 + schk * 8);
      bf16x8 vbg = *(const bf16x8*)(cfg.WTg + (size_t)(n_blk + srow) * K + k0 + schk * 8);
      __syncthreads();
      *(bf16x8*)&As[srow * AS_STRIDE + schk * 8] = va0;
      *(bf16x8*)&As[(64 + srow) * AS_STRIDE + schk * 8] = va1;
      *(bf16x8*)&Bhs[srow * BS_STRIDE + schk * 8] = vbh;
      *(bf16x8*)&Bgs[srow * BS_STRIDE + schk * 8] = vbg;
      __syncthreads();

      bf16x8 af0 = *(const bf16x8*)&As[(wave * 32 + col) * AS_STRIDE + q * 8];
      bf16x8 af1 = *(const bf16x8*)&As[(wave * 32 + 16 + col) * AS_STRIDE + q * 8];
      #pragma unroll
      for (int ns = 0; ns < 4; ++ns) {
        bf16x8 bfh = *(const bf16x8*)&Bhs[(ns * 16 + col) * BS_STRIDE + q * 8];
        bf16x8 bfg = *(const bf16x8*)&Bgs[(ns * 16 + col) * BS_STRIDE + q * 8];
        acch[0][ns] = __builtin_amdgcn_mfma_f32_16x16x32_bf16(af0, bfh, acch[0][ns], 0, 0, 0);
        acch[1][ns] = __builtin_amdgcn_mfma_f32_16x16x32_bf16(af1, bfh, acch[1][ns], 0, 0, 0);
        accg[0][ns] = __builtin_amdgcn_mfma_f32_16x16x32_bf16(af0, bfg, accg[0][ns], 0, 0, 0);
        accg[1][ns] = __builtin_amdgcn_mfma_f32_16x16x32_bf16(af1, bfg, accg[1][ns], 0, 0, 0);
      }
    }
  }

  // Epilogue. C/D layout: col = lane&15, row = quad*4 + reg.
  #pragma unroll
  for (int ms = 0; ms < 2; ++ms) {
    const int m_base = m_blk + wave * 32 + ms * 16 + q * 4;
    #pragma unroll
    for (int ns = 0; ns < 4; ++ns) {
      const int n = n_blk + ns * 16 + col;
      const float bhv = cfg.bh[n];
      const float bgv = cfg.bg[n];
      #pragma unroll
      for (int r = 0; r < 4; ++r) {
        const int m = m_base + r;
        if (m >= count) continue;
        const float hv = fast_tanh(acch[ms][ns][r] + bhv) * fast_sigmoid(accg[ms][ns][r] + bgv);
        if (cfg.out_mode == 0) {
          hbase[(size_t)m * H_DIM + n] = f2bf(hv);
        } else {
          p.out[(size_t)cfg.idx[m] * H_DIM + n] = hv;
        }
      }
    }
  }
}

// ---------------------------------------------------------------------------
// Finisher: zero children rows with g==2 (rows g0/g1 are written by scatter),
// write float mask for all rows. One row per wave, 4 rows per block.
// ---------------------------------------------------------------------------
__global__ __launch_bounds__(256)
void finish_k(const int* __restrict__ group, float* __restrict__ children,
              float* __restrict__ mask) {
  const int row = blockIdx.x * 4 + (threadIdx.x >> 6);
  const int lane = threadIdx.x & 63;
  const int g = group[row];
  if (lane == 0) mask[row] = (g == 2) ? 1.0f : 0.0f;
  if (g == 2) {
    const f32x4 z4 = {0.f, 0.f, 0.f, 0.f};
    f32x4* pr = (f32x4*)(children + (size_t)row * H_DIM);
    pr[lane] = z4;
    pr[lane + 64] = z4;
  }
}

// ---------------------------------------------------------------------------
// Fallback path (R3-proven, 25 MiB ws): full-B gated GEMM, no compaction.
// ---------------------------------------------------------------------------
template<int NSEG, bool OUT_BF16, bool SELECT>
__global__ __launch_bounds__(256, 2)
void gate_gemm_fb(const float* __restrict__ f0, const float* __restrict__ f1,
                  const float* __restrict__ f2, const ushort_t* __restrict__ b0,
                  const ushort_t* __restrict__ WTh, const ushort_t* __restrict__ WTg,
                  const float* __restrict__ bh, const float* __restrict__ bg,
                  void* __restrict__ out_v, const int* __restrict__ group)
{
  constexpr int K = NSEG * 512;
  __shared__ ushort_t As[128 * AS_STRIDE];
  __shared__ ushort_t Bhs[64 * BS_STRIDE];
  __shared__ ushort_t Bgs[64 * BS_STRIDE];

  const int t = threadIdx.x;
  const int lane = t & 63;
  const int wave = t >> 6;
  const int m_blk = blockIdx.x * 128;
  const int n_blk = blockIdx.y * 64;

  const f32x4 zero4 = {0.f, 0.f, 0.f, 0.f};
  f32x4 acch[2][4], accg[2][4];
  #pragma unroll
  for (int i = 0; i < 2; ++i)
    #pragma unroll
    for (int j = 0; j < 4; ++j) { acch[i][j] = zero4; accg[i][j] = zero4; }

  const int srow = t >> 2;
  const int schk = t & 3;
  const int q = lane >> 4;
  const int col = lane & 15;

  #pragma unroll
  for (int s = 0; s < NSEG; ++s) {
    const bool seg_bf16 = (s == 0) && (b0 != nullptr);
    const float* fp = (s == 0) ? f0 : ((s == 1) ? f1 : f2);
    for (int kk = 0; kk < 512; kk += 32) {
      const int k0 = s * 512 + kk;
      bf16x8 va0, va1;
      if (seg_bf16) {
        va0 = *(const bf16x8*)(b0 + (size_t)(m_blk + srow) * H_DIM + kk + schk * 8);
        va1 = *(const bf16x8*)(b0 + (size_t)(m_blk + 64 + srow) * H_DIM + kk + schk * 8);
      } else {
        va0 = cvt8(fp + (size_t)(m_blk + srow) * H_DIM + kk + schk * 8);
        va1 = cvt8(fp + (size_t)(m_blk + 64 + srow) * H_DIM + kk + schk * 8);
      }
      bf16x8 vbh = *(const bf16x8*)(WTh + (size_t)(n_blk + srow) * K + k0 + schk * 8);
      bf16x8 vbg = *(const bf16x8*)(WTg + (size_t)(n_blk + srow) * K + k0 + schk * 8);
      __syncthreads();
      *(bf16x8*)&As[srow * AS_STRIDE + schk * 8] = va0;
      *(bf16x8*)&As[(64 + srow) * AS_STRIDE + schk * 8] = va1;
      *(bf16x8*)&Bhs[srow * BS_STRIDE + schk * 8] = vbh;
      *(bf16x8*)&Bgs[srow * BS_STRIDE + schk * 8] = vbg;
      __syncthreads();

      bf16x8 af0 = *(const bf16x8*)&As[(wave * 32 + col) * AS_STRIDE + q * 8];
      bf16x8 af1 = *(const bf16x8*)&As[(wave * 32 + 16 + col) * AS_STRIDE + q * 8];
      #pragma unroll
      for (int ns = 0; ns < 4; ++ns) {
        bf16x8 bfh = *(const bf16x8*)&Bhs[(ns * 16 + col) * BS_STRIDE + q * 8];
        bf16x8 bfg = *(const bf16x8*)&Bgs[(ns * 16 + col) * BS_STRIDE + q * 8];
        acch[0][ns] = __builtin_amdgcn_mfma_f32_16x16x32_bf16(af0, bfh, acch[0][ns], 0, 0, 0);
        acch[1][ns] = __builtin_amdgcn_mfma_f32_16x16x32_bf16(af1, bfh, acch[1][ns], 0, 0, 0);
        accg[0][ns] = __builtin_amdgcn_mfma_f32_16x16x32_bf16(af0, bfg, accg[0][ns], 0, 0, 0);
        accg[1][ns] = __builtin_amdgcn_mfma_f32_16x16x32_bf16(af1, bfg, accg[1][ns], 0, 0, 0);
      }
    }
  }

  #pragma unroll
  for (int ms = 0; ms < 2; ++ms) {
    const int m_base = m_blk + wave * 32 + ms * 16 + q * 4;
    #pragma unroll
    for (int ns = 0; ns < 4; ++ns) {
      const int n = n_blk + ns * 16 + col;
      const float bhv = bh[n];
      const float bgv = bg[n];
      #pragma unroll
      for (int r = 0; r < 4; ++r) {
        const int m = m_base + r;
        float hv = fast_tanh(acch[ms][ns][r] + bhv) * fast_sigmoid(accg[ms][ns][r] + bgv);
        if (OUT_BF16) {
          ((ushort_t*)out_v)[(size_t)m * H_DIM + n] = f2bf(hv);
        } else {
          float* po = (float*)out_v + (size_t)m * H_DIM + n;
          if (SELECT) {
            const int g = group[m];
            const float rv = *po;
            hv = (g == 0) ? hv : ((g == 1) ? rv : 0.0f);
          }
          *po = hv;
        }
      }
    }
  }
}

__global__ __launch_bounds__(256)
void mask_k(const int* __restrict__ group, float* __restrict__ out_mask) {
  const int i = blockIdx.x * 256 + threadIdx.x;
  out_mask[i] = (group[i] == 2) ? 1.0f : 0.0f;
}

extern "C" void kernel_launch(void* const* d_in, const int* in_sizes, int n_in,
                              void* d_out, int out_size, void* d_ws, size_t ws_size,
                              hipStream_t stream) {
  const float* node_hidden     = (const float*)d_in[0];
  const float* node_context    = (const float*)d_in[1];
  const float* label_embedding = (const float*)d_in[2];
  const float* left_embedding  = (const float*)d_in[3];
  const int*   group           = (const int*)d_in[4];
  const float* Wl1h = (const float*)d_in[5];
  const float* bl1h = (const float*)d_in[6];
  const float* Wl1g = (const float*)d_in[7];
  const float* bl1g = (const float*)d_in[8];
  const float* Wl2h = (const float*)d_in[9];
  const float* bl2h = (const float*)d_in[10];
  const float* Wl2g = (const float*)d_in[11];
  const float* bl2g = (const float*)d_in[12];
  const float* Wr1h = (const float*)d_in[13];
  const float* br1h = (const float*)d_in[14];
  const float* Wr1g = (const float*)d_in[15];
  const float* br1g = (const float*)d_in[16];
  const float* Wr2h = (const float*)d_in[17];
  const float* br2h = (const float*)d_in[18];
  const float* Wr2g = (const float*)d_in[19];
  const float* br2g = (const float*)d_in[20];

  // --- Workspace layout (WT region shared by both paths) ---
  char* ws = (char*)d_ws;
  const size_t w3 = (size_t)512 * 1536;
  const size_t w1 = (size_t)512 * 512;
  const size_t w2 = (size_t)512 * 1024;
  ushort_t* WT_l1h = (ushort_t*)ws;   ws += w3 * 2;
  ushort_t* WT_l1g = (ushort_t*)ws;   ws += w3 * 2;
  ushort_t* WT_r1h = (ushort_t*)ws;   ws += w3 * 2;
  ushort_t* WT_r1g = (ushort_t*)ws;   ws += w3 * 2;
  ushort_t* WT_l2h = (ushort_t*)ws;   ws += w1 * 2;
  ushort_t* WT_l2g = (ushort_t*)ws;   ws += w1 * 2;
  ushort_t* WT_r2h = (ushort_t*)ws;   ws += w2 * 2;
  ushort_t* WT_r2g = (ushort_t*)ws;   ws += w2 * 2;   // 9,437,184 B so far

  float* out_children = (float*)d_out;
  float* out_mask     = out_children + (size_t)B_ROWS * H_DIM;

  // Fast path extra: idx0/idx1 (256 KB), cnt, h_buf (33,024 rows bf16)
  const size_t fast_need = 9437184 + 2 * (size_t)B_ROWS * 4 + 256
                         + (size_t)33024 * H_DIM * 2;
  const bool fast = ws_size >= fast_need;

  // Fused transposes (1 launch, both paths use WT buffers)
  TransposeParams tp;
  tp.src[0] = Wl1h; tp.dst[0] = WT_l1h; tp.K[0] = 1536;
  tp.src[1] = Wl1g; tp.dst[1] = WT_l1g; tp.K[1] = 1536;
  tp.src[2] = Wr1h; tp.dst[2] = WT_r1h; tp.K[2] = 1536;
  tp.src[3] = Wr1g; tp.dst[3] = WT_r1g; tp.K[3] = 1536;
  tp.src[4] = Wl2h; tp.dst[4] = WT_l2h; tp.K[4] = 512;
  tp.src[5] = Wl2g; tp.dst[5] = WT_l2g; tp.K[5] = 512;
  tp.src[6] = Wr2h; tp.dst[6] = WT_r2h; tp.K[6] = 1024;
  tp.src[7] = Wr2g; tp.dst[7] = WT_r2g; tp.K[7] = 1024;
  transpose_all<<<dim3(16, 48, 8), dim3(32, 8), 0, stream>>>(tp);

  if (fast) {
    int* idx0 = (int*)ws;                 ws += (size_t)B_ROWS * 4;
    int* idx1 = (int*)ws;                 ws += (size_t)B_ROWS * 4;
    int* cnt  = (int*)ws;                 ws += 256;
    ushort_t* h_buf = (ushort_t*)ws;

    compact_k<<<1, 1024, 0, stream>>>(group, idx0, idx1, cnt);

    GemmParams p1;  // layer 1, both paths: h = gate1(gather[nh|nc|le])
    p1.h_buf = h_buf; p1.out = nullptr; p1.cnt = cnt;
    p1.c[0].f0 = node_hidden; p1.c[0].f1 = node_context; p1.c[0].f2 = label_embedding;
    p1.c[0].WTh = WT_l1h; p1.c[0].WTg = WT_l1g; p1.c[0].bh = bl1h; p1.c[0].bg = bl1g;
    p1.c[0].idx = idx0; p1.c[0].nseg = 3; p1.c[0].b0_is_h = 0;
    p1.c[0].out_mode = 0; p1.c[0].cnt_slot = 0; p1.c[0].h_off_cnt0 = 0;
    p1.c[1] = p1.c[0];
    p1.c[1].WTh = WT_r1h; p1.c[1].WTg = WT_r1g; p1.c[1].bh = br1h; p1.c[1].bg = br1g;
    p1.c[1].idx = idx1; p1.c[1].cnt_slot = 1; p1.c[1].h_off_cnt0 = 1;
    gate_gemm_c<<<dim3(B_ROWS / 128, H_DIM / 64, 2), dim3(256), 0, stream>>>(p1);

    GemmParams p2;  // layer 2, both paths, scatter to out
    p2.h_buf = h_buf; p2.out = out_children; p2.cnt = cnt;
    p2.c[0].f0 = nullptr; p2.c[0].f1 = nullptr; p2.c[0].f2 = nullptr;
    p2.c[0].WTh = WT_l2h; p2.c[0].WTg = WT_l2g; p2.c[0].bh = bl2h; p2.c[0].bg = bl2g;
    p2.c[0].idx = idx0; p2.c[0].nseg = 1; p2.c[0].b0_is_h = 1;
    p2.c[0].out_mode = 1; p2.c[0].cnt_slot = 0; p2.c[0].h_off_cnt0 = 0;
    p2.c[1] = p2.c[0];
    p2.c[1].f1 = left_embedding;
    p2.c[1].WTh = WT_r2h; p2.c[1].WTg = WT_r2g; p2.c[1].bh = br2h; p2.c[1].bg = br2g;
    p2.c[1].idx = idx1; p2.c[1].nseg = 2; p2.c[1].cnt_slot = 1; p2.c[1].h_off_cnt0 = 1;
    gate_gemm_c<<<dim3(B_ROWS / 128, H_DIM / 64, 2), dim3(256), 0, stream>>>(p2);

    finish_k<<<B_ROWS / 4, 256, 0, stream>>>(group, out_children, out_mask);
  } else {
    // R3-proven fallback (25 MiB ws)
    ushort_t* h_buf = (ushort_t*)ws;   // 16384 x 512 bf16
    dim3 gg(M_CHUNK / 128, H_DIM / 64);
    dim3 gb(256);
    for (int c = 0; c < B_ROWS / M_CHUNK; ++c) {
      const size_t ro = (size_t)c * M_CHUNK;
      const float* nh = node_hidden     + ro * H_DIM;
      const float* nc = node_context    + ro * H_DIM;
      const float* le = label_embedding + ro * H_DIM;
      const float* lf = left_embedding  + ro * H_DIM;
      float* oc = out_children + ro * H_DIM;
      const int* gp = group + ro;
      gate_gemm_fb<3, true, false><<<gg, gb, 0, stream>>>(nh, nc, le, nullptr,
          WT_r1h, WT_r1g, br1h, br1g, h_buf, nullptr);
      gate_gemm_fb<2, false, false><<<gg, gb, 0, stream>>>(nullptr, lf, nullptr, h_buf,
          WT_r2h, WT_r2g, br2h, br2g, oc, nullptr);
      gate_gemm_fb<3, true, false><<<gg, gb, 0, stream>>>(nh, nc, le, nullptr,
          WT_l1h, WT_l1g, bl1h, bl1g, h_buf, nullptr);
      gate_gemm_fb<1, false, true><<<gg, gb, 0, stream>>>(nullptr, nullptr, nullptr, h_buf,
          WT_l2h, WT_l2g, bl2h, bl2g, oc, gp);
    }
    mask_k<<<B_ROWS / 256, 256, 0, stream>>>(group, out_mask);
  }
}